// Round 1
// 983.326 us; speedup vs baseline: 1.0693x; 1.0693x over previous
//
#include <hip/hip_runtime.h>
#include <hip/hip_bf16.h>

#define NIN 32
#define NHID 128
#define NOUT 16
#define NIN1 160   // NIN+NHID
#define SEQT 512
#define NB 256
#define SEGI 40    // i's per segment (4 segments x 128 o = 512 threads)

#if defined(__has_builtin)
#if __has_builtin(__builtin_amdgcn_fdot2_f32_bf16)
#define HAVE_DOT2BF 1
#endif
#endif
#ifndef HAVE_DOT2BF
#define HAVE_DOT2BF 0
#endif

// manual RNE f32->bf16 (inputs are finite/sane here)
__device__ __forceinline__ unsigned int f2bfbits(float f) {
    unsigned int u = __float_as_uint(f);
    return (u + 0x7fffu + ((u >> 16) & 1u)) >> 16;
}
__device__ __forceinline__ unsigned int packbf(float lo, float hi) {
    return f2bfbits(lo) | (f2bfbits(hi) << 16);
}

#if HAVE_DOT2BF
typedef __bf16 bf16x2 __attribute__((ext_vector_type(2)));
__device__ __forceinline__ float dot2w(unsigned int a, unsigned int b, float c) {
    return __builtin_amdgcn_fdot2_f32_bf16(__builtin_bit_cast(bf16x2, a),
                                           __builtin_bit_cast(bf16x2, b), c, false);
}
#else
__device__ __forceinline__ float dot2w(unsigned int a, unsigned int b, float c) {
    float alo = __uint_as_float(a << 16), ahi = __uint_as_float(a & 0xffff0000u);
    float blo = __uint_as_float(b << 16), bhi = __uint_as_float(b & 0xffff0000u);
    return __builtin_fmaf(ahi, bhi, __builtin_fmaf(alo, blo, c));
}
#endif

// Knots: t_m = -8.8 + 1.6*m (G=5, K=3, range [-4,4]).
// UNIFORM knots -> Cox-de Boor collapses to the closed-form uniform cubic basis:
//   v0=(1-f)^3/6, v1=(4-6f^2+3f^3)/6, v2=(1+3f+3f^2-3f^3)/6, v3=f^3/6
// (checked: partition of unity, C2 continuity at knots; edge truncation in the
// reference only DROPS entries — kept entries keep the uniform values, so the
// js clamp/shift logic below is unchanged from the verified recursion version).
__device__ __forceinline__ void spline_feat(float c, float* out4, int* jst) {
    const float t0 = -8.8f, inv_h = 0.625f;   // 1/1.6 == 0.625 exactly
    float u  = (c - t0) * inv_h;
    float uf = floorf(u);
    int   m0 = (int)uf;
    bool valid = (m0 >= 0) && (m0 <= 10);
    float f   = u - uf;                        // in [0,1)
    float omf = 1.0f - f;
    float f2 = f * f,     f3 = f2 * f;
    float omf3 = omf * omf * omf;
    const float c6 = 0.16666667f;
    float v0 = omf3 * c6;
    float v1 = __builtin_fmaf(3.0f, f3, __builtin_fmaf(-6.0f, f2, 4.0f)) * c6;
    float v2 = __builtin_fmaf(-3.0f, f3, __builtin_fmaf(3.0f, f + f2, 1.0f)) * c6;
    float v3 = f3 * c6;
    float v[4] = {v0, v1, v2, v3};
    int jb = m0 - 3;
    int js = jb < 0 ? 0 : (jb > 4 ? 4 : jb);
    int sh = js - jb;
    #pragma unroll
    for (int r = 0; r < 4; ++r) {
        int rs = r + sh;
        out4[r] = (valid && rs >= 0 && rs <= 3) ? v[rs] : 0.f;
    }
    *jst = js;
}

// fast silu: 1-ulp rcp is fine (features are bf16-rounded anyway; epilogue err ~1e-7)
__device__ __forceinline__ float fsilu(float c) {
    return c * __builtin_amdgcn_rcpf(1.f + __expf(-c));
}

// X-macro: 20 weight pairs per thread (covers 40 i's), ALL named scalars -> no alloca,
// nothing the compiler can demote to scratch.
#define R20(X) X(0) X(1) X(2) X(3) X(4) X(5) X(6) X(7) X(8) X(9) \
               X(10) X(11) X(12) X(13) X(14) X(15) X(16) X(17) X(18) X(19)

__attribute__((amdgpu_waves_per_eu(2, 2)))   // pin EXACTLY 2 waves/EU -> 256-VGPR budget
__global__ void __launch_bounds__(512)
kan_seq(const float* __restrict__ x,
        const float* __restrict__ coef1,
        const float* __restrict__ sb1,
        const float* __restrict__ sp1,
        const float* __restrict__ coef2,
        const float* __restrict__ sb2,
        const float* __restrict__ sp2,
        float* __restrict__ out)
{
    __shared__ __align__(16) unsigned int Fb[NIN1][4];  // 8 bf16 basis per record
    __shared__ float Fsil[NIN1];                        // silu per record
    __shared__ float red[4][NHID];                      // per-seg partial sums
    __shared__ float Hf[NHID][9];                       // epilogue h-features (f32)

    const int tid  = threadIdx.x;
    const int b    = blockIdx.x;           // one batch row per block
    const int o    = tid & 127;
    const int seg  = tid >> 7;             // 0..3
    const int i0   = seg * SEGI;
    const int lane = tid & 63;

    // ---- one-time: layer-1 weights -> NAMED registers, bf16-packed, sp1 folded ----
#define DECLP(p) uint4 wA##p, wB##p; unsigned int sbp##p;
    R20(DECLP)
#undef DECLP

#define INITP(p) { \
    const int iA = i0 + 2 * (p), iB = i0 + 2 * (p) + 1; \
    const float4* ca = (const float4*)(coef1 + (size_t)(iA * NHID + o) * 8); \
    const float4* cb = (const float4*)(coef1 + (size_t)(iB * NHID + o) * 8); \
    float spA = sp1[iA * NHID + o], spB = sp1[iB * NHID + o]; \
    float4 a0 = ca[0], a1 = ca[1], b0v = cb[0], b1v = cb[1]; \
    wA##p = make_uint4(packbf(spA * a0.x, spA * a0.y), packbf(spA * a0.z, spA * a0.w), \
                       packbf(spA * a1.x, spA * a1.y), packbf(spA * a1.z, spA * a1.w)); \
    wB##p = make_uint4(packbf(spB * b0v.x, spB * b0v.y), packbf(spB * b0v.z, spB * b0v.w), \
                       packbf(spB * b1v.x, spB * b1v.y), packbf(spB * b1v.z, spB * b1v.w)); \
    sbp##p = packbf(sb1[iA * NHID + o], sb1[iB * NHID + o]); }
    R20(INITP)
#undef INITP

    ((float*)red)[tid] = 0.f;   // h0 = 0 (red is exactly 512 floats)
    float xv = (tid < NIN) ? x[(size_t)b * SEQT * NIN + tid] : 0.f;
    __syncthreads();

    for (int t = 0; t < SEQT; ++t) {
        // ---- phase 1: features (silu + sparse basis) for all 160 inputs ----
        if (tid < NIN1) {
            float c;
            if (tid < NIN) c = xv;
            else {
                int hi = tid - NIN;
                c = red[0][hi] + red[1][hi] + red[2][hi] + red[3][hi];
            }
            float sil = fsilu(c);
            float b4[4]; int js;
            spline_feat(c, b4, &js);
            float e[8];
            #pragma unroll
            for (int k = 0; k < 8; ++k) {
                int d = k - js;
                e[k] = (d >= 0 && d < 4) ? b4[d] : 0.f;
            }
            uint4 pk;
            pk.x = packbf(e[0], e[1]); pk.y = packbf(e[2], e[3]);
            pk.z = packbf(e[4], e[5]); pk.w = packbf(e[6], e[7]);
            *(uint4*)&Fb[tid][0] = pk;
            Fsil[tid] = sil;
        }
        if (tid < NIN) {   // prefetch next timestep's x
            int tn = (t + 1 < SEQT) ? (t + 1) : t;
            xv = x[((size_t)b * SEQT + tn) * NIN + tid];
        }
        __syncthreads();

        // ---- phase 2: named-register weights x LDS-broadcast features ----
        // 2-deep software pipeline on the feature reads: macro p's dots cover
        // macro p+1's ds_read_b128 latency (only 2 waves/SIMD -> can't rely on TLP).
        float vsil = Fsil[i0 + (lane < SEGI ? lane : 0)];  // lane-parallel silu preload
        uint4 pfA = *(const uint4*)&Fb[i0][0];
        uint4 pfB = *(const uint4*)&Fb[i0 + 1][0];
        float ac0 = 0.f, ac1 = 0.f, ac2 = 0.f, ac3 = 0.f;
#define DOTP(p) { \
        uint4 bA = pfA, bB = pfB; \
        if ((p) < SEGI / 2 - 1) { \
            pfA = *(const uint4*)&Fb[i0 + 2 * (p) + 2][0]; \
            pfB = *(const uint4*)&Fb[i0 + 2 * (p) + 3][0]; \
        } \
        float sb_lo = __uint_as_float(sbp##p << 16); \
        float sb_hi = __uint_as_float(sbp##p & 0xffff0000u); \
        float slA = __int_as_float(__builtin_amdgcn_readlane(__float_as_int(vsil), 2 * (p))); \
        float slB = __int_as_float(__builtin_amdgcn_readlane(__float_as_int(vsil), 2 * (p) + 1)); \
        ac0 = __builtin_fmaf(slA, sb_lo, ac0); \
        ac0 = dot2w(bA.x, wA##p.x, ac0); ac1 = dot2w(bA.y, wA##p.y, ac1); \
        ac2 = dot2w(bA.z, wA##p.z, ac2); ac3 = dot2w(bA.w, wA##p.w, ac3); \
        ac1 = __builtin_fmaf(slB, sb_hi, ac1); \
        ac0 = dot2w(bB.x, wB##p.x, ac0); ac1 = dot2w(bB.y, wB##p.y, ac1); \
        ac2 = dot2w(bB.z, wB##p.z, ac2); ac3 = dot2w(bB.w, wB##p.w, ac3); }
        R20(DOTP)
#undef DOTP
        red[seg][o] = (ac0 + ac1) + (ac2 + ac3);
        __syncthreads();
    }

    // ---- layer 2 on final h only (fp32; verified in rounds 3-4) ----
    if (tid < NHID) {
        float c = red[0][tid] + red[1][tid] + red[2][tid] + red[3][tid];
        float sil = fsilu(c);
        float b4[4]; int js;
        spline_feat(c, b4, &js);
        #pragma unroll
        for (int k = 0; k < 8; ++k) {
            int d = k - js;
            Hf[tid][k] = (d >= 0 && d < 4) ? b4[d] : 0.f;
        }
        Hf[tid][8] = sil;
    }
    __syncthreads();
    if (tid < 128) {
        int o2 = tid & 15, isg = tid >> 4;     // 8 i-groups of 16
        float acc = 0.f;
        for (int q = 0; q < 16; ++q) {
            int i = isg * 16 + q;
            const float* c2 = coef2 + (size_t)(i * NOUT + o2) * 8;
            float s = 0.f;
            #pragma unroll
            for (int k = 0; k < 8; ++k) s += Hf[i][k] * c2[k];
            acc += Hf[i][8] * sb2[i * NOUT + o2] + sp2[i * NOUT + o2] * s;
        }
        ((float*)red)[isg * 16 + o2] = acc;
    }
    __syncthreads();
    if (tid < NOUT) {
        float a = 0.f;
        #pragma unroll
        for (int g = 0; g < 8; ++g) a += ((float*)red)[g * 16 + tid];
        out[(size_t)b * NOUT + tid] = a;
    }
}

extern "C" void kernel_launch(void* const* d_in, const int* in_sizes, int n_in,
                              void* d_out, int out_size, void* d_ws, size_t ws_size,
                              hipStream_t stream) {
    kan_seq<<<NB, 512, 0, stream>>>(
        (const float*)d_in[0], (const float*)d_in[1], (const float*)d_in[2],
        (const float*)d_in[3], (const float*)d_in[4], (const float*)d_in[5],
        (const float*)d_in[6], (float*)d_out);
}